// Round 28
// baseline (209.320 us; speedup 1.0000x reference)
//
#include <hip/hip_runtime.h>
#include <hip/hip_bf16.h>

typedef short v8s __attribute__((ext_vector_type(8)));
typedef float v4f __attribute__((ext_vector_type(4)));
typedef unsigned int v4u __attribute__((ext_vector_type(4)));
typedef unsigned int v2u __attribute__((ext_vector_type(2)));

#define DEV static __device__ __forceinline__
#define AS1 __attribute__((address_space(1)))
#define AS3 __attribute__((address_space(3)))

DEV float bf2f(unsigned short u){ unsigned int x=((unsigned int)u)<<16; float f; __builtin_memcpy(&f,&x,4); return f; }
DEV float bf2fhi(unsigned int u){ unsigned int x=u&0xffff0000u; float f; __builtin_memcpy(&f,&x,4); return f; }
DEV short f2bf(float f){ __hip_bfloat16 h=__float2bfloat16(f); short s; __builtin_memcpy(&s,&h,2); return s; }
// packed fp32x2 -> bf16x2 RTNE via intrinsic (lowered to v_cvt_pk_bf16_f32 on gfx950)
DEV unsigned int pk2(float a, float b){
  __hip_bfloat162 h = __float22bfloat162_rn(make_float2(a,b));
  unsigned r; __builtin_memcpy(&r,&h,4); return r;
}
DEV v4f mfma16(v8s a, v8s b, v4f c){ return __builtin_amdgcn_mfma_f32_16x16x32_bf16(a,b,c,0,0,0); }
// bare v_exp_f32 (2^x): __expf = v_mul(log2e) + v_exp; libm exp2f = slow OCML. This is 1 op.
DEV float fexp2(float x){
#if __has_builtin(__builtin_amdgcn_exp2f)
  return __builtin_amdgcn_exp2f(x);
#else
  float r; asm("v_exp_f32 %0, %1" : "=v"(r) : "v"(x)); return r;
#endif
}

// ---------------- fp32 -> bf16 pre-conversion (x, Wq, Wk, Wv) ----------------
__global__ __launch_bounds__(256) void convert_kernel(
    const float* __restrict__ x,  const float* __restrict__ Wq,
    const float* __restrict__ Wk, const float* __restrict__ Wv,
    short* __restrict__ xb, short* __restrict__ wqb,
    short* __restrict__ wkb, short* __restrict__ wvb)
{
  unsigned g = blockIdx.x*256u + threadIdx.x;
  const float* src; short* dst; unsigned off;
  if (g < 1048576u){ src=x;  dst=xb;  off=g; }
  else if (g < 1310720u){ src=Wq; dst=wqb; off=g-1048576u; }
  else if (g < 1572864u){ src=Wk; dst=wkb; off=g-1310720u; }
  else { src=Wv; dst=wvb; off=g-1572864u; }
  v4f f = *(const v4f*)(src + (size_t)off*4);
  v2u r; r[0]=pk2(f[0],f[1]); r[1]=pk2(f[2],f[3]);
  *(v2u*)(dst + (size_t)off*4) = r;
}

// ---------------- fp32 -> bf16 conversion for Wo (runs AFTER attn, into dead q_ws) -------
__global__ __launch_bounds__(256) void convertW_kernel(const float* __restrict__ src,
                                                       short* __restrict__ dst)
{
  unsigned off = blockIdx.x*256u + threadIdx.x;   // 262144 groups of 4
  v4f f = *(const v4f*)(src + (size_t)off*4);
  v2u r; r[0]=pk2(f[0],f[1]); r[1]=pk2(f[2],f[3]);
  *(v2u*)(dst + (size_t)off*4) = r;
}

// ---------------- bf16 128x128 GEMM core, T3 2-phase global_load_lds dbuf ----------------
DEV void gemm_core16(const short* __restrict__ A, const short* __restrict__ Bmat,
                     int brow0, int bn0, int tid, short* As, short* Bs, v4f acc[4][4])
{
  const int l = tid & 63, w = tid >> 6;
  const int wr = (w>>1)*64, wc = (w&1)*64;
  const int row = tid>>2, p = tid&3;
  const int sw = (p^((row>>1)&3))*8;        // same for row and row+64 (32 ≡ 0 mod 4)
  auto STAGE=[&](int kt,int buf){
    const short* a0 = A    + (size_t)(brow0+row   )*1024 + kt*32 + sw;
    const short* a1 = A    + (size_t)(brow0+row+64)*1024 + kt*32 + sw;
    const short* b0 = Bmat + (size_t)(bn0 +row   )*1024 + kt*32 + sw;
    const short* b1 = Bmat + (size_t)(bn0 +row+64)*1024 + kt*32 + sw;
    __builtin_amdgcn_global_load_lds((const AS1 void*)a0,(AS3 void*)(As+buf*4096+(size_t)tid*8),16,0,0);
    __builtin_amdgcn_global_load_lds((const AS1 void*)a1,(AS3 void*)(As+buf*4096+(size_t)(tid+256)*8),16,0,0);
    __builtin_amdgcn_global_load_lds((const AS1 void*)b0,(AS3 void*)(Bs+buf*4096+(size_t)tid*8),16,0,0);
    __builtin_amdgcn_global_load_lds((const AS1 void*)b1,(AS3 void*)(Bs+buf*4096+(size_t)(tid+256)*8),16,0,0);
  };
  STAGE(0,0);
  asm volatile("s_waitcnt vmcnt(0)" ::: "memory");
  __builtin_amdgcn_s_barrier();
  int cur=0;
  for (int kt=0; kt<32; ++kt){
    if (kt<31) STAGE(kt+1,cur^1);            // next tile flies during MFMA below
    v8s af[4], bfr[4];
    #pragma unroll
    for (int m=0;m<4;++m){ int r=wr+m*16+(l&15); af[m]=*(const v8s*)&As[cur*4096+(r*4+((l>>4)^((r>>1)&3)))*8]; }
    #pragma unroll
    for (int n=0;n<4;++n){ int r=wc+n*16+(l&15); bfr[n]=*(const v8s*)&Bs[cur*4096+(r*4+((l>>4)^((r>>1)&3)))*8]; }
    #pragma unroll
    for (int m=0;m<4;++m)
      #pragma unroll
      for (int n=0;n<4;++n)
        acc[m][n]=mfma16(af[m],bfr[n],acc[m][n]);
    asm volatile("s_waitcnt vmcnt(0)" ::: "memory");
    __builtin_amdgcn_s_barrier();
    cur^=1;
  }
}

// ---------------- fused QKV projection ----------------
// Q stored PRE-SCALED by 0.125*log2(e) so attn uses bare v_exp_f32 (2^x).
// V stored PERMUTED within each 32-key chunk so attn's PV A-fragment needs no shuffles.
__global__ __launch_bounds__(256) void qkv_gemm(const short* __restrict__ xb,
    const short* __restrict__ wqb, const short* __restrict__ wkb, const short* __restrict__ wvb,
    const float* __restrict__ bq, const float* __restrict__ bk, const float* __restrict__ bv,
    short* __restrict__ qo, short* __restrict__ ko, short* __restrict__ vfo)
{
  __shared__ short As[8192], Bs[8192];
  const int tid=threadIdx.x, l=tid&63, w=tid>>6;
  const int bcol0=blockIdx.x*128, brow0=blockIdx.y*128;
  const int mat=bcol0>>10, n0=bcol0&1023;
  const short* Wm   = mat==0?wqb:(mat==1?wkb:wvb);
  const float* bias = mat==0?bq:(mat==1?bk:bv);
  v4f acc[4][4];
  v4f vz={0.f,0.f,0.f,0.f};
  #pragma unroll
  for(int m=0;m<4;++m)
    #pragma unroll
    for(int n=0;n<4;++n) acc[m][n]=vz;
  gemm_core16(xb, Wm, brow0, n0, tid, As, Bs, acc);
  const int wr=(w>>1)*64, wc=(w&1)*64;
  const float qscale = 0.18033688011112042f;   // 0.125 * log2(e)
  #pragma unroll
  for(int m=0;m<4;++m)
  #pragma unroll
  for(int n=0;n<4;++n)
  #pragma unroll
  for(int r=0;r<4;++r){
    int row=brow0+wr+m*16+(l>>4)*4+r;       // 0..4095  (b*2048+s)
    int col=n0+wc+n*16+(l&15);              // 0..1023 within mat
    float v=acc[m][n][r]+bias[col];
    int b=row>>11, s=row&2047, h=col>>6, dk=col&63;
    int bh=b*16+h;
    if(mat==0)      qo[((size_t)bh*2048+s)*64+dk]=f2bf(v*qscale);
    else if(mat==1) ko[((size_t)bh*2048+s)*64+dk]=f2bf(v);
    else{
      int kb=s>>9, c=(s>>5)&15, ki=s&31;
      int g2=(ki>>2)&3, j=(ki>>4)*4+(ki&3);
      int lane2=g2*16+(dk&15);
      vfo[((((size_t)bh*4+kb)*16+c)*4+(size_t)(dk>>4))*512 + lane2*8 + j]=f2bf(v);
    }
  }
}

// ---------------- per-(bh,kb) V column sums, 4-wave parallel ----------------
__global__ __launch_bounds__(256) void vbsum_kernel(const short* __restrict__ vf, float* __restrict__ vbp)
{
  __shared__ float red[4][4][16];     // [wave][dt][d16]
  const int bh=blockIdx.x, kb=blockIdx.y, tid=threadIdx.x, wv=tid>>6, l=tid&63;
  const short* base = vf + ((size_t)(bh*4+kb))*16*4*512;
  float acc[4]={0.f,0.f,0.f,0.f};
  #pragma unroll
  for(int cc=0;cc<4;++cc){
    int c=wv*4+cc;
    #pragma unroll
    for(int dt=0;dt<4;++dt){
      v8s vv=*(const v8s*)(base + ((size_t)(c*4+dt))*512 + l*8);
      float s=0.f;
      #pragma unroll
      for(int j=0;j<8;++j) s+=bf2f((unsigned short)vv[j]);
      acc[dt]+=s;
    }
  }
  #pragma unroll
  for(int dt=0;dt<4;++dt){
    acc[dt]+=__shfl_xor(acc[dt],16);
    acc[dt]+=__shfl_xor(acc[dt],32);
  }
  if(l<16){
    #pragma unroll
    for(int dt=0;dt<4;++dt) red[wv][dt][l]=acc[dt];
  }
  __syncthreads();
  if(tid<64){
    int dt=tid>>4, d=tid&15;
    float s=(red[0][dt][d]+red[1][dt][d])+(red[2][dt][d]+red[3][dt][d]);
    vbp[(size_t)(bh*4+kb)*64 + dt*16 + d]=s;
  }
}

// ---------------- fused double-softmax attention: SINGLE-PASS, PIPELINED K ----------
// 64KB kbuf holds a FULL 512-key window (both halves). Per window: sync -> QKE x32 ->
// sync -> issue next window's staging (flies under PVC) -> d1 + PVC. 2 barriers/window
// (was 4), staging hidden under PVC. Balanced pair per block (qt=31-y then y, 5 windows).
// Grid (32 bh,16 y)=512 blocks=2/CU; LDS 64KB -> 128KB/CU fits. No caps (R9/R21/R26).
__global__ __launch_bounds__(256) void attn_kernel(
  const short* __restrict__ q, const short* __restrict__ k, const short* __restrict__ vf,
  const float* __restrict__ vbp, short* __restrict__ attn)
{
  __shared__ short kbuf[32768];       // 64KB: 512 keys x 64d, XOR-swizzled 16B slots
  const int tid=threadIdx.x, l=tid&63, wv=tid>>6;
  const int bh=blockIdx.x;
  const int g=l>>4, q16=l&15;
  const int b=bh>>4, h=bh&15;

  const short* qbase = q + (size_t)bh*2048*64;
  const short* kbase = k + (size_t)bh*2048*64;
  v4f vz={0.f,0.f,0.f,0.f};

  auto stage=[&](int kb2,int hb2){
    #pragma unroll
    for (int i=0;i<8;++i){
      int idx=i*256+tid, key=idx>>3, p=idx&7, pp=p^(key&7);
      const short* gp = kbase + (size_t)(kb2*512+hb2*256+key)*64 + pp*8;
      __builtin_amdgcn_global_load_lds((const AS1 void*)gp,
          (AS3 void*)((char*)kbuf + hb2*32768 + idx*16), 16, 0, 0);
    }
  };

// QK^T tile CT (0..31, full window) -> exp2'd scores packed into sc16, d1acc accumulated
#define QKE(CT)                                                         \
  { int krow=(CT)*16+q16;                                               \
    int s0=g^(krow&7), s1=(g+4)^(krow&7);                               \
    v8s k0=*(const v8s*)&kbuf[(krow*8+s0)*8];                           \
    v8s k1=*(const v8s*)&kbuf[(krow*8+s1)*8];                           \
    v4f t=mfma16(k0,qa0,vz);                                            \
    v4f e4=mfma16(k1,qa1,t);                                            \
    v4f ev;                                                             \
    _Pragma("unroll")                                                   \
    for (int r=0;r<4;++r){                                              \
      float s=e4[r];                                                    \
      if (diag && kb*512+(CT)*16+g*4+r > qglob) s=-1e38f;               \
      ev[r]=fexp2(s);                                                   \
      d1acc+=ev[r];                                                     \
    }                                                                   \
    sc16[(CT)*2]=pk2(ev[0],ev[1]); sc16[(CT)*2+1]=pk2(ev[2],ev[3]);     \
  }

// PV chunk C from cached scores: w = 2^(e*d1i) - 1
#define PVC(C)                                                          \
  { unsigned a0=sc16[4*(C)], a1=sc16[4*(C)+1];                          \
    unsigned b0=sc16[4*(C)+2], b1=sc16[4*(C)+3];                        \
    float w0=fexp2(bf2f((unsigned short)(a0&0xffffu))*d1i)-1.0f;        \
    float w1=fexp2(bf2fhi(a0)*d1i)-1.0f;                                \
    float w2=fexp2(bf2f((unsigned short)(a1&0xffffu))*d1i)-1.0f;        \
    float w3=fexp2(bf2fhi(a1)*d1i)-1.0f;                                \
    float w4=fexp2(bf2f((unsigned short)(b0&0xffffu))*d1i)-1.0f;        \
    float w5=fexp2(bf2fhi(b0)*d1i)-1.0f;                                \
    float w6=fexp2(bf2f((unsigned short)(b1&0xffffu))*d1i)-1.0f;        \
    float w7=fexp2(bf2fhi(b1)*d1i)-1.0f;                                \
    zacc+=((w0+w1)+(w2+w3))+((w4+w5)+(w6+w7));                          \
    union { v4u u; v8s s; } pa;                                         \
    pa.u[0]=pk2(w0,w1); pa.u[1]=pk2(w2,w3);                             \
    pa.u[2]=pk2(w4,w5); pa.u[3]=pk2(w6,w7);                             \
    const short* vfp = vf + ((((size_t)bh*4+kb)*16+(C))*4)*512 + l*8;   \
    _Pragma("unroll")                                                   \
    for (int dt=0;dt<4;++dt){                                           \
      v8s vfr=*(const v8s*)(vfp + (size_t)dt*512);                      \
      o[dt]=mfma16(pa.s,vfr,o[dt]);                                     \
    }                                                                   \
  }

  #pragma unroll 1
  for (int half=0; half<2; ++half){
    const int qt = half ? (int)blockIdx.y : 31-(int)blockIdx.y;  // heavy then light: 5 windows total
    const int qb = qt>>3;
    const int qrow0 = qt*64+wv*16;
    const int qglob = qrow0+q16;
    const short* qp = qbase + (size_t)(qrow0+q16)*64 + g*8;
    v8s qa0=*(const v8s*)qp, qa1=*(const v8s*)(qp+32);

    v4f o[4];
    #pragma unroll
    for(int dt=0;dt<4;++dt) o[dt]=vz;
    float zacc=0.f;
    unsigned sc16[64];                // 32 tiles x 4 scores, 2^x applied, packed bf16 pairs

    // half1 needed unless this window is the diag AND the q-tile sits in the low half
    const bool hi4 = ((qt&7)>=4);
    stage(0,0); if (qb>0 || hi4) stage(0,1);
    #pragma unroll 1
    for (int kb=0; kb<=qb; ++kb){
      const bool diag=(kb==qb);
      // pair-rounded last live tile (odd): extra tile fully masked -> stores exact 0s
      const int tmax2 = diag ? (((qt&7)*4+wv)|1) : 31;
      float d1acc=0.f;
      __syncthreads();                // drains staged loads: window kb fully resident
      #pragma unroll
      for (int ct=0;ct<32;++ct) if (ct<=tmax2) QKE(ct)
      __syncthreads();                // all waves done reading kbuf
      if (kb<qb){                     // prefetch next window; flies under PVC below
        stage(kb+1,0);
        if (kb+1<qb || hi4) stage(kb+1,1);
      }
      float d1=d1acc;
      d1+=__shfl_xor(d1,16); d1+=__shfl_xor(d1,32);
      const float d1i=1.44269504f/d1;
      #pragma unroll
      for (int c=0;c<16;++c) if (2*c<=tmax2) PVC(c)
    }

    // ---- epilogue: Z per q-row, baseline = total V sum (weight 1), Z base 2048 ----
    float z=zacc;
    z+=__shfl_xor(z,16); z+=__shfl_xor(z,32);
    float base[4];
    #pragma unroll
    for (int dt=0;dt<4;++dt){
      float s=0.f;
      #pragma unroll
      for (int kk=0;kk<4;++kk) s+=vbp[(size_t)(bh*4+kk)*64 + dt*16 + q16];
      base[dt]=s;
    }
    #pragma unroll
    for (int r=0;r<4;++r){
      float zr=__shfl(z, g*4+r);
      float inv=1.0f/(2048.0f+zr);
      int rowi=qrow0+g*4+r;
      size_t obase=((size_t)b*2048+rowi)*1024 + h*64;
      #pragma unroll
      for (int dt=0;dt<4;++dt)
        attn[obase + dt*16 + q16] = f2bf((o[dt][r]+base[dt])*inv);
    }
  }
#undef QKE
#undef PVC
}

// ---------------- output projection (A bf16, B bf16 pre-converted, out fp32) -------------
__global__ __launch_bounds__(256) void oproj_gemm(const short* __restrict__ at,
    const short* __restrict__ wob, const float* __restrict__ bo, float* __restrict__ out)
{
  __shared__ short As[8192], Bs[8192];
  const int tid=threadIdx.x, l=tid&63, w=tid>>6;
  const int bcol0=blockIdx.x*128, brow0=blockIdx.y*128;
  v4f acc[4][4];
  v4f vz={0.f,0.f,0.f,0.f};
  #pragma unroll
  for(int m=0;m<4;++m)
    #pragma unroll
    for(int n=0;n<4;++n) acc[m][n]=vz;
  gemm_core16(at, wob, brow0, bcol0, tid, As, Bs, acc);
  const int wr=(w>>1)*64, wc=(w&1)*64;
  #pragma unroll
  for(int m=0;m<4;++m)
  #pragma unroll
  for(int n=0;n<4;++n)
  #pragma unroll
  for(int r=0;r<4;++r){
    int row=brow0+wr+m*16+(l>>4)*4+r;
    int col=bcol0+wc+n*16+(l&15);
    out[(size_t)row*1024+col]=acc[m][n][r]+bo[col];
  }
}

extern "C" void kernel_launch(void* const* d_in, const int* in_sizes, int n_in,
                              void* d_out, int out_size, void* d_ws, size_t ws_size,
                              hipStream_t stream)
{
  const float* x  =(const float*)d_in[0];
  const float* Wq =(const float*)d_in[1];
  const float* bq =(const float*)d_in[2];
  const float* Wk =(const float*)d_in[3];
  const float* bk =(const float*)d_in[4];
  const float* Wv =(const float*)d_in[5];
  const float* bv =(const float*)d_in[6];
  const float* Wo =(const float*)d_in[7];
  const float* bo =(const float*)d_in[8];
  float* out=(float*)d_out;
  char* ws=(char*)d_ws;
  // ws (32 MiB): [0,8M)=xb then at_ws; [8M)=q then wob (q dead after attn); [16M)=k; [24M)=vf.
  // d_out doubles as scratch until oproj overwrites it:
  //   [0,2M)=wqb, [2M,4M)=wkb, [4M,6M)=wvb (bf16), [7M)=vbp (fp32, 32KB).
  short* xb_ws =(short*)(ws);
  short* at_ws =(short*)(ws);
  short* q_ws  =(short*)(ws + ((size_t)8<<20));
  short* wob_ws=(short*)(ws + ((size_t)8<<20));
  short* k_ws  =(short*)(ws + ((size_t)16<<20));
  short* vf_ws =(short*)(ws + ((size_t)24<<20));
  char*  outb  =(char*)d_out;
  short* wqb   =(short*)(outb);
  short* wkb   =(short*)(outb + ((size_t)2<<20));
  short* wvb   =(short*)(outb + ((size_t)4<<20));
  float* vbp_ws=(float*)(outb + ((size_t)7<<20));

  convert_kernel<<<dim3(7168),256,0,stream>>>(x,Wq,Wk,Wv,xb_ws,wqb,wkb,wvb);
  qkv_gemm<<<dim3(24,32),256,0,stream>>>(xb_ws,wqb,wkb,wvb,bq,bk,bv,q_ws,k_ws,vf_ws);
  vbsum_kernel<<<dim3(32,4),256,0,stream>>>(vf_ws,vbp_ws);
  attn_kernel<<<dim3(32,16),256,0,stream>>>(q_ws,k_ws,vf_ws,vbp_ws,at_ws);
  convertW_kernel<<<dim3(1024),256,0,stream>>>(Wo,wob_ws);
  oproj_gemm<<<dim3(8,32),256,0,stream>>>(at_ws,wob_ws,bo,out);
}

// Round 29
// 145.452 us; speedup vs baseline: 1.4391x; 1.4391x over previous
//
#include <hip/hip_runtime.h>
#include <hip/hip_bf16.h>

typedef short v8s __attribute__((ext_vector_type(8)));
typedef float v4f __attribute__((ext_vector_type(4)));
typedef unsigned int v4u __attribute__((ext_vector_type(4)));
typedef unsigned int v2u __attribute__((ext_vector_type(2)));

#define DEV static __device__ __forceinline__
#define AS1 __attribute__((address_space(1)))
#define AS3 __attribute__((address_space(3)))

DEV float bf2f(unsigned short u){ unsigned int x=((unsigned int)u)<<16; float f; __builtin_memcpy(&f,&x,4); return f; }
DEV float bf2fhi(unsigned int u){ unsigned int x=u&0xffff0000u; float f; __builtin_memcpy(&f,&x,4); return f; }
DEV short f2bf(float f){ __hip_bfloat16 h=__float2bfloat16(f); short s; __builtin_memcpy(&s,&h,2); return s; }
// packed fp32x2 -> bf16x2 RTNE via intrinsic (lowered to v_cvt_pk_bf16_f32 on gfx950)
DEV unsigned int pk2(float a, float b){
  __hip_bfloat162 h = __float22bfloat162_rn(make_float2(a,b));
  unsigned r; __builtin_memcpy(&r,&h,4); return r;
}
DEV v4f mfma16(v8s a, v8s b, v4f c){ return __builtin_amdgcn_mfma_f32_16x16x32_bf16(a,b,c,0,0,0); }
// bare v_exp_f32 (2^x): __expf = v_mul(log2e) + v_exp; libm exp2f = slow OCML. This is 1 op.
DEV float fexp2(float x){
#if __has_builtin(__builtin_amdgcn_exp2f)
  return __builtin_amdgcn_exp2f(x);
#else
  float r; asm("v_exp_f32 %0, %1" : "=v"(r) : "v"(x)); return r;
#endif
}

// ---------------- fp32 -> bf16 pre-conversion (x, Wq, Wk, Wv) ----------------
__global__ __launch_bounds__(256) void convert_kernel(
    const float* __restrict__ x,  const float* __restrict__ Wq,
    const float* __restrict__ Wk, const float* __restrict__ Wv,
    short* __restrict__ xb, short* __restrict__ wqb,
    short* __restrict__ wkb, short* __restrict__ wvb)
{
  unsigned g = blockIdx.x*256u + threadIdx.x;
  const float* src; short* dst; unsigned off;
  if (g < 1048576u){ src=x;  dst=xb;  off=g; }
  else if (g < 1310720u){ src=Wq; dst=wqb; off=g-1048576u; }
  else if (g < 1572864u){ src=Wk; dst=wkb; off=g-1310720u; }
  else { src=Wv; dst=wvb; off=g-1572864u; }
  v4f f = *(const v4f*)(src + (size_t)off*4);
  v2u r; r[0]=pk2(f[0],f[1]); r[1]=pk2(f[2],f[3]);
  *(v2u*)(dst + (size_t)off*4) = r;
}

// ---------------- fp32 -> bf16 conversion for Wo (runs AFTER attn, into dead q_ws) -------
__global__ __launch_bounds__(256) void convertW_kernel(const float* __restrict__ src,
                                                       short* __restrict__ dst)
{
  unsigned off = blockIdx.x*256u + threadIdx.x;   // 262144 groups of 4
  v4f f = *(const v4f*)(src + (size_t)off*4);
  v2u r; r[0]=pk2(f[0],f[1]); r[1]=pk2(f[2],f[3]);
  *(v2u*)(dst + (size_t)off*4) = r;
}

// ---------------- bf16 128x128 GEMM core, T3 2-phase global_load_lds dbuf ----------------
DEV void gemm_core16(const short* __restrict__ A, const short* __restrict__ Bmat,
                     int brow0, int bn0, int tid, short* As, short* Bs, v4f acc[4][4])
{
  const int l = tid & 63, w = tid >> 6;
  const int wr = (w>>1)*64, wc = (w&1)*64;
  const int row = tid>>2, p = tid&3;
  const int sw = (p^((row>>1)&3))*8;        // same for row and row+64 (32 ≡ 0 mod 4)
  auto STAGE=[&](int kt,int buf){
    const short* a0 = A    + (size_t)(brow0+row   )*1024 + kt*32 + sw;
    const short* a1 = A    + (size_t)(brow0+row+64)*1024 + kt*32 + sw;
    const short* b0 = Bmat + (size_t)(bn0 +row   )*1024 + kt*32 + sw;
    const short* b1 = Bmat + (size_t)(bn0 +row+64)*1024 + kt*32 + sw;
    __builtin_amdgcn_global_load_lds((const AS1 void*)a0,(AS3 void*)(As+buf*4096+(size_t)tid*8),16,0,0);
    __builtin_amdgcn_global_load_lds((const AS1 void*)a1,(AS3 void*)(As+buf*4096+(size_t)(tid+256)*8),16,0,0);
    __builtin_amdgcn_global_load_lds((const AS1 void*)b0,(AS3 void*)(Bs+buf*4096+(size_t)tid*8),16,0,0);
    __builtin_amdgcn_global_load_lds((const AS1 void*)b1,(AS3 void*)(Bs+buf*4096+(size_t)(tid+256)*8),16,0,0);
  };
  STAGE(0,0);
  asm volatile("s_waitcnt vmcnt(0)" ::: "memory");
  __builtin_amdgcn_s_barrier();
  int cur=0;
  for (int kt=0; kt<32; ++kt){
    if (kt<31) STAGE(kt+1,cur^1);            // next tile flies during MFMA below
    v8s af[4], bfr[4];
    #pragma unroll
    for (int m=0;m<4;++m){ int r=wr+m*16+(l&15); af[m]=*(const v8s*)&As[cur*4096+(r*4+((l>>4)^((r>>1)&3)))*8]; }
    #pragma unroll
    for (int n=0;n<4;++n){ int r=wc+n*16+(l&15); bfr[n]=*(const v8s*)&Bs[cur*4096+(r*4+((l>>4)^((r>>1)&3)))*8]; }
    #pragma unroll
    for (int m=0;m<4;++m)
      #pragma unroll
      for (int n=0;n<4;++n)
        acc[m][n]=mfma16(af[m],bfr[n],acc[m][n]);
    asm volatile("s_waitcnt vmcnt(0)" ::: "memory");
    __builtin_amdgcn_s_barrier();
    cur^=1;
  }
}

// ---------------- fused QKV projection ----------------
// Q stored PRE-SCALED by 0.125*log2(e) so attn uses bare v_exp_f32 (2^x).
// V stored PERMUTED within each 32-key chunk so attn's PV A-fragment needs no shuffles.
__global__ __launch_bounds__(256) void qkv_gemm(const short* __restrict__ xb,
    const short* __restrict__ wqb, const short* __restrict__ wkb, const short* __restrict__ wvb,
    const float* __restrict__ bq, const float* __restrict__ bk, const float* __restrict__ bv,
    short* __restrict__ qo, short* __restrict__ ko, short* __restrict__ vfo)
{
  __shared__ short As[8192], Bs[8192];
  const int tid=threadIdx.x, l=tid&63, w=tid>>6;
  const int bcol0=blockIdx.x*128, brow0=blockIdx.y*128;
  const int mat=bcol0>>10, n0=bcol0&1023;
  const short* Wm   = mat==0?wqb:(mat==1?wkb:wvb);
  const float* bias = mat==0?bq:(mat==1?bk:bv);
  v4f acc[4][4];
  v4f vz={0.f,0.f,0.f,0.f};
  #pragma unroll
  for(int m=0;m<4;++m)
    #pragma unroll
    for(int n=0;n<4;++n) acc[m][n]=vz;
  gemm_core16(xb, Wm, brow0, n0, tid, As, Bs, acc);
  const int wr=(w>>1)*64, wc=(w&1)*64;
  const float qscale = 0.18033688011112042f;   // 0.125 * log2(e)
  #pragma unroll
  for(int m=0;m<4;++m)
  #pragma unroll
  for(int n=0;n<4;++n)
  #pragma unroll
  for(int r=0;r<4;++r){
    int row=brow0+wr+m*16+(l>>4)*4+r;       // 0..4095  (b*2048+s)
    int col=n0+wc+n*16+(l&15);              // 0..1023 within mat
    float v=acc[m][n][r]+bias[col];
    int b=row>>11, s=row&2047, h=col>>6, dk=col&63;
    int bh=b*16+h;
    if(mat==0)      qo[((size_t)bh*2048+s)*64+dk]=f2bf(v*qscale);
    else if(mat==1) ko[((size_t)bh*2048+s)*64+dk]=f2bf(v);
    else{
      int kb=s>>9, c=(s>>5)&15, ki=s&31;
      int g2=(ki>>2)&3, j=(ki>>4)*4+(ki&3);
      int lane2=g2*16+(dk&15);
      vfo[((((size_t)bh*4+kb)*16+c)*4+(size_t)(dk>>4))*512 + lane2*8 + j]=f2bf(v);
    }
  }
}

// ---------------- per-(bh,kb) V column sums, 4-wave parallel ----------------
__global__ __launch_bounds__(256) void vbsum_kernel(const short* __restrict__ vf, float* __restrict__ vbp)
{
  __shared__ float red[4][4][16];     // [wave][dt][d16]
  const int bh=blockIdx.x, kb=blockIdx.y, tid=threadIdx.x, wv=tid>>6, l=tid&63;
  const short* base = vf + ((size_t)(bh*4+kb))*16*4*512;
  float acc[4]={0.f,0.f,0.f,0.f};
  #pragma unroll
  for(int cc=0;cc<4;++cc){
    int c=wv*4+cc;
    #pragma unroll
    for(int dt=0;dt<4;++dt){
      v8s vv=*(const v8s*)(base + ((size_t)(c*4+dt))*512 + l*8);
      float s=0.f;
      #pragma unroll
      for(int j=0;j<8;++j) s+=bf2f((unsigned short)vv[j]);
      acc[dt]+=s;
    }
  }
  #pragma unroll
  for(int dt=0;dt<4;++dt){
    acc[dt]+=__shfl_xor(acc[dt],16);
    acc[dt]+=__shfl_xor(acc[dt],32);
  }
  if(l<16){
    #pragma unroll
    for(int dt=0;dt<4;++dt) red[wv][dt][l]=acc[dt];
  }
  __syncthreads();
  if(tid<64){
    int dt=tid>>4, d=tid&15;
    float s=(red[0][dt][d]+red[1][dt][d])+(red[2][dt][d]+red[3][dt][d]);
    vbp[(size_t)(bh*4+kb)*64 + dt*16 + d]=s;
  }
}

// ---------------- fused double-softmax attention: SINGLE-PASS, bf16 score cache ----------
// LOAD-BALANCED: each block does TWO q-tiles sequentially, qt=31-y (heavy) then qt=y
// (light) -> exactly 5 windows per block for every y (dispatch-order independent, G16).
// Grid (32 bh, 16 y) = 512 blocks = 2/CU, all co-resident, uniform finish.
// NO launch-bounds cap (caps spill/squeeze: R9/R21/R26); no setprio (R18); bh fast (R22);
// 32KB kbuf (64KB pipelining regressed: R28).
__global__ __launch_bounds__(256) void attn_kernel(
  const short* __restrict__ q, const short* __restrict__ k, const short* __restrict__ vf,
  const float* __restrict__ vbp, short* __restrict__ attn)
{
  __shared__ short kbuf[16384];       // 32KB: 256 keys x 64d, XOR-swizzled 16B slots
  const int tid=threadIdx.x, l=tid&63, wv=tid>>6;
  const int bh=blockIdx.x;
  const int g=l>>4, q16=l&15;
  const int b=bh>>4, h=bh&15;

  const short* qbase = q + (size_t)bh*2048*64;
  const short* kbase = k + (size_t)bh*2048*64;
  v4f vz={0.f,0.f,0.f,0.f};

  auto stage=[&](int kb2,int hb2){
    #pragma unroll
    for (int i=0;i<8;++i){
      int idx=i*256+tid, key=idx>>3, p=idx&7, pp=p^(key&7);
      const short* gp = kbase + (size_t)(kb2*512+hb2*256+key)*64 + pp*8;
      __builtin_amdgcn_global_load_lds((const AS1 void*)gp,
          (AS3 void*)((char*)kbuf + idx*16), 16, 0, 0);
    }
  };

// QK^T tile CT -> exp2'd scores packed into sc16, d1acc accumulated
#define QKE(CT)                                                         \
  { int krow=((CT)&15)*16+q16;                                          \
    int s0=g^(krow&7), s1=(g+4)^(krow&7);                               \
    v8s k0=*(const v8s*)&kbuf[(krow*8+s0)*8];                           \
    v8s k1=*(const v8s*)&kbuf[(krow*8+s1)*8];                           \
    v4f t=mfma16(k0,qa0,vz);                                            \
    v4f e4=mfma16(k1,qa1,t);                                            \
    v4f ev;                                                             \
    _Pragma("unroll")                                                   \
    for (int r=0;r<4;++r){                                              \
      float s=e4[r];                                                    \
      if (diag && kb*512+(CT)*16+g*4+r > qglob) s=-1e38f;               \
      ev[r]=fexp2(s);                                                   \
      d1acc+=ev[r];                                                     \
    }                                                                   \
    sc16[(CT)*2]=pk2(ev[0],ev[1]); sc16[(CT)*2+1]=pk2(ev[2],ev[3]);     \
  }

// PV chunk C from cached scores: w = 2^(e*d1i) - 1
#define PVC(C)                                                          \
  { unsigned a0=sc16[4*(C)], a1=sc16[4*(C)+1];                          \
    unsigned b0=sc16[4*(C)+2], b1=sc16[4*(C)+3];                        \
    float w0=fexp2(bf2f((unsigned short)(a0&0xffffu))*d1i)-1.0f;        \
    float w1=fexp2(bf2fhi(a0)*d1i)-1.0f;                                \
    float w2=fexp2(bf2f((unsigned short)(a1&0xffffu))*d1i)-1.0f;        \
    float w3=fexp2(bf2fhi(a1)*d1i)-1.0f;                                \
    float w4=fexp2(bf2f((unsigned short)(b0&0xffffu))*d1i)-1.0f;        \
    float w5=fexp2(bf2fhi(b0)*d1i)-1.0f;                                \
    float w6=fexp2(bf2f((unsigned short)(b1&0xffffu))*d1i)-1.0f;        \
    float w7=fexp2(bf2fhi(b1)*d1i)-1.0f;                                \
    zacc+=((w0+w1)+(w2+w3))+((w4+w5)+(w6+w7));                          \
    union { v4u u; v8s s; } pa;                                         \
    pa.u[0]=pk2(w0,w1); pa.u[1]=pk2(w2,w3);                             \
    pa.u[2]=pk2(w4,w5); pa.u[3]=pk2(w6,w7);                             \
    const short* vfp = vf + ((((size_t)bh*4+kb)*16+(C))*4)*512 + l*8;   \
    _Pragma("unroll")                                                   \
    for (int dt=0;dt<4;++dt){                                           \
      v8s vfr=*(const v8s*)(vfp + (size_t)dt*512);                      \
      o[dt]=mfma16(pa.s,vfr,o[dt]);                                     \
    }                                                                   \
  }

  #pragma unroll 1
  for (int half=0; half<2; ++half){
    const int qt = half ? (int)blockIdx.y : 31-(int)blockIdx.y;  // heavy then light: 5 windows total
    const int qb = qt>>3;
    const int qrow0 = qt*64+wv*16;
    const int qglob = qrow0+q16;
    const short* qp = qbase + (size_t)(qrow0+q16)*64 + g*8;
    v8s qa0=*(const v8s*)qp, qa1=*(const v8s*)(qp+32);

    v4f o[4];
    #pragma unroll
    for(int dt=0;dt<4;++dt) o[dt]=vz;
    float zacc=0.f;
    unsigned sc16[64];                // 32 tiles x 4 scores, 2^x applied, packed bf16 pairs

    for (int kb=0; kb<=qb; ++kb){
      const bool diag=(kb==qb);
      // pair-rounded last live tile (odd): extra tile fully masked -> stores exact 0s
      const int tmax2 = diag ? (((qt&7)*4+wv)|1) : 31;
      const int blkhi = diag ? ((qt&7)*4+3) : 31;  // block-uniform
      float d1acc=0.f;
      stage(kb,0); __syncthreads();
      #pragma unroll
      for (int ct=0;ct<16;++ct) if (ct<=tmax2) QKE(ct)
      __syncthreads();
      if (blkhi>=16){
        stage(kb,1); __syncthreads();
        #pragma unroll
        for (int ct=16;ct<32;++ct) if (ct<=tmax2) QKE(ct)
        __syncthreads();
      }
      float d1=d1acc;
      d1+=__shfl_xor(d1,16); d1+=__shfl_xor(d1,32);
      const float d1i=1.44269504f/d1;
      #pragma unroll
      for (int c=0;c<16;++c) if (2*c<=tmax2) PVC(c)
    }

    // ---- epilogue: Z per q-row, baseline = total V sum (weight 1), Z base 2048 ----
    float z=zacc;
    z+=__shfl_xor(z,16); z+=__shfl_xor(z,32);
    float base[4];
    #pragma unroll
    for (int dt=0;dt<4;++dt){
      float s=0.f;
      #pragma unroll
      for (int kk=0;kk<4;++kk) s+=vbp[(size_t)(bh*4+kk)*64 + dt*16 + q16];
      base[dt]=s;
    }
    #pragma unroll
    for (int r=0;r<4;++r){
      float zr=__shfl(z, g*4+r);
      float inv=1.0f/(2048.0f+zr);
      int rowi=qrow0+g*4+r;
      size_t obase=((size_t)b*2048+rowi)*1024 + h*64;
      #pragma unroll
      for (int dt=0;dt<4;++dt)
        attn[obase + dt*16 + q16] = f2bf((o[dt][r]+base[dt])*inv);
    }
  }
#undef QKE
#undef PVC
}

// ---------------- output projection (A bf16, B bf16 pre-converted, out fp32) -------------
__global__ __launch_bounds__(256) void oproj_gemm(const short* __restrict__ at,
    const short* __restrict__ wob, const float* __restrict__ bo, float* __restrict__ out)
{
  __shared__ short As[8192], Bs[8192];
  const int tid=threadIdx.x, l=tid&63, w=tid>>6;
  const int bcol0=blockIdx.x*128, brow0=blockIdx.y*128;
  v4f acc[4][4];
  v4f vz={0.f,0.f,0.f,0.f};
  #pragma unroll
  for(int m=0;m<4;++m)
    #pragma unroll
    for(int n=0;n<4;++n) acc[m][n]=vz;
  gemm_core16(at, wob, brow0, bcol0, tid, As, Bs, acc);
  const int wr=(w>>1)*64, wc=(w&1)*64;
  #pragma unroll
  for(int m=0;m<4;++m)
  #pragma unroll
  for(int n=0;n<4;++n)
  #pragma unroll
  for(int r=0;r<4;++r){
    int row=brow0+wr+m*16+(l>>4)*4+r;
    int col=bcol0+wc+n*16+(l&15);
    out[(size_t)row*1024+col]=acc[m][n][r]+bo[col];
  }
}

extern "C" void kernel_launch(void* const* d_in, const int* in_sizes, int n_in,
                              void* d_out, int out_size, void* d_ws, size_t ws_size,
                              hipStream_t stream)
{
  const float* x  =(const float*)d_in[0];
  const float* Wq =(const float*)d_in[1];
  const float* bq =(const float*)d_in[2];
  const float* Wk =(const float*)d_in[3];
  const float* bk =(const float*)d_in[4];
  const float* Wv =(const float*)d_in[5];
  const float* bv =(const float*)d_in[6];
  const float* Wo =(const float*)d_in[7];
  const float* bo =(const float*)d_in[8];
  float* out=(float*)d_out;
  char* ws=(char*)d_ws;
  // ws (32 MiB): [0,8M)=xb then at_ws; [8M)=q then wob (q dead after attn); [16M)=k; [24M)=vf.
  // d_out doubles as scratch until oproj overwrites it:
  //   [0,2M)=wqb, [2M,4M)=wkb, [4M,6M)=wvb (bf16), [7M)=vbp (fp32, 32KB).
  short* xb_ws =(short*)(ws);
  short* at_ws =(short*)(ws);
  short* q_ws  =(short*)(ws + ((size_t)8<<20));
  short* wob_ws=(short*)(ws + ((size_t)8<<20));
  short* k_ws  =(short*)(ws + ((size_t)16<<20));
  short* vf_ws =(short*)(ws + ((size_t)24<<20));
  char*  outb  =(char*)d_out;
  short* wqb   =(short*)(outb);
  short* wkb   =(short*)(outb + ((size_t)2<<20));
  short* wvb   =(short*)(outb + ((size_t)4<<20));
  float* vbp_ws=(float*)(outb + ((size_t)7<<20));

  convert_kernel<<<dim3(7168),256,0,stream>>>(x,Wq,Wk,Wv,xb_ws,wqb,wkb,wvb);
  qkv_gemm<<<dim3(24,32),256,0,stream>>>(xb_ws,wqb,wkb,wvb,bq,bk,bv,q_ws,k_ws,vf_ws);
  vbsum_kernel<<<dim3(32,4),256,0,stream>>>(vf_ws,vbp_ws);
  attn_kernel<<<dim3(32,16),256,0,stream>>>(q_ws,k_ws,vf_ws,vbp_ws,at_ws);
  convertW_kernel<<<dim3(1024),256,0,stream>>>(Wo,wob_ws);
  oproj_gemm<<<dim3(8,32),256,0,stream>>>(at_ws,wob_ws,bo,out);
}

// Round 30
// 145.356 us; speedup vs baseline: 1.4401x; 1.0007x over previous
//
#include <hip/hip_runtime.h>
#include <hip/hip_bf16.h>

typedef short v8s __attribute__((ext_vector_type(8)));
typedef float v4f __attribute__((ext_vector_type(4)));
typedef unsigned int v4u __attribute__((ext_vector_type(4)));
typedef unsigned int v2u __attribute__((ext_vector_type(2)));

#define DEV static __device__ __forceinline__
#define AS1 __attribute__((address_space(1)))
#define AS3 __attribute__((address_space(3)))

DEV float bf2f(unsigned short u){ unsigned int x=((unsigned int)u)<<16; float f; __builtin_memcpy(&f,&x,4); return f; }
DEV float bf2fhi(unsigned int u){ unsigned int x=u&0xffff0000u; float f; __builtin_memcpy(&f,&x,4); return f; }
DEV short f2bf(float f){ __hip_bfloat16 h=__float2bfloat16(f); short s; __builtin_memcpy(&s,&h,2); return s; }
// packed fp32x2 -> bf16x2 RTNE via intrinsic (lowered to v_cvt_pk_bf16_f32 on gfx950)
DEV unsigned int pk2(float a, float b){
  __hip_bfloat162 h = __float22bfloat162_rn(make_float2(a,b));
  unsigned r; __builtin_memcpy(&r,&h,4); return r;
}
DEV v4f mfma16(v8s a, v8s b, v4f c){ return __builtin_amdgcn_mfma_f32_16x16x32_bf16(a,b,c,0,0,0); }
// bare v_exp_f32 (2^x): __expf = v_mul(log2e) + v_exp; libm exp2f = slow OCML. This is 1 op.
DEV float fexp2(float x){
#if __has_builtin(__builtin_amdgcn_exp2f)
  return __builtin_amdgcn_exp2f(x);
#else
  float r; asm("v_exp_f32 %0, %1" : "=v"(r) : "v"(x)); return r;
#endif
}

// ---------------- fp32 -> bf16 pre-conversion (x, Wq, Wk, Wv) ----------------
__global__ __launch_bounds__(256) void convert_kernel(
    const float* __restrict__ x,  const float* __restrict__ Wq,
    const float* __restrict__ Wk, const float* __restrict__ Wv,
    short* __restrict__ xb, short* __restrict__ wqb,
    short* __restrict__ wkb, short* __restrict__ wvb)
{
  unsigned g = blockIdx.x*256u + threadIdx.x;
  const float* src; short* dst; unsigned off;
  if (g < 1048576u){ src=x;  dst=xb;  off=g; }
  else if (g < 1310720u){ src=Wq; dst=wqb; off=g-1048576u; }
  else if (g < 1572864u){ src=Wk; dst=wkb; off=g-1310720u; }
  else { src=Wv; dst=wvb; off=g-1572864u; }
  v4f f = *(const v4f*)(src + (size_t)off*4);
  v2u r; r[0]=pk2(f[0],f[1]); r[1]=pk2(f[2],f[3]);
  *(v2u*)(dst + (size_t)off*4) = r;
}

// ---------------- fp32 -> bf16 conversion for Wo (runs AFTER attn, into dead q_ws) -------
__global__ __launch_bounds__(256) void convertW_kernel(const float* __restrict__ src,
                                                       short* __restrict__ dst)
{
  unsigned off = blockIdx.x*256u + threadIdx.x;   // 262144 groups of 4
  v4f f = *(const v4f*)(src + (size_t)off*4);
  v2u r; r[0]=pk2(f[0],f[1]); r[1]=pk2(f[2],f[3]);
  *(v2u*)(dst + (size_t)off*4) = r;
}

// ---------------- bf16 128x128 GEMM core, T3 2-phase global_load_lds dbuf ----------------
DEV void gemm_core16(const short* __restrict__ A, const short* __restrict__ Bmat,
                     int brow0, int bn0, int tid, short* As, short* Bs, v4f acc[4][4])
{
  const int l = tid & 63, w = tid >> 6;
  const int wr = (w>>1)*64, wc = (w&1)*64;
  const int row = tid>>2, p = tid&3;
  const int sw = (p^((row>>1)&3))*8;        // same for row and row+64 (32 ≡ 0 mod 4)
  auto STAGE=[&](int kt,int buf){
    const short* a0 = A    + (size_t)(brow0+row   )*1024 + kt*32 + sw;
    const short* a1 = A    + (size_t)(brow0+row+64)*1024 + kt*32 + sw;
    const short* b0 = Bmat + (size_t)(bn0 +row   )*1024 + kt*32 + sw;
    const short* b1 = Bmat + (size_t)(bn0 +row+64)*1024 + kt*32 + sw;
    __builtin_amdgcn_global_load_lds((const AS1 void*)a0,(AS3 void*)(As+buf*4096+(size_t)tid*8),16,0,0);
    __builtin_amdgcn_global_load_lds((const AS1 void*)a1,(AS3 void*)(As+buf*4096+(size_t)(tid+256)*8),16,0,0);
    __builtin_amdgcn_global_load_lds((const AS1 void*)b0,(AS3 void*)(Bs+buf*4096+(size_t)tid*8),16,0,0);
    __builtin_amdgcn_global_load_lds((const AS1 void*)b1,(AS3 void*)(Bs+buf*4096+(size_t)(tid+256)*8),16,0,0);
  };
  STAGE(0,0);
  asm volatile("s_waitcnt vmcnt(0)" ::: "memory");
  __builtin_amdgcn_s_barrier();
  int cur=0;
  for (int kt=0; kt<32; ++kt){
    if (kt<31) STAGE(kt+1,cur^1);            // next tile flies during MFMA below
    v8s af[4], bfr[4];
    #pragma unroll
    for (int m=0;m<4;++m){ int r=wr+m*16+(l&15); af[m]=*(const v8s*)&As[cur*4096+(r*4+((l>>4)^((r>>1)&3)))*8]; }
    #pragma unroll
    for (int n=0;n<4;++n){ int r=wc+n*16+(l&15); bfr[n]=*(const v8s*)&Bs[cur*4096+(r*4+((l>>4)^((r>>1)&3)))*8]; }
    #pragma unroll
    for (int m=0;m<4;++m)
      #pragma unroll
      for (int n=0;n<4;++n)
        acc[m][n]=mfma16(af[m],bfr[n],acc[m][n]);
    asm volatile("s_waitcnt vmcnt(0)" ::: "memory");
    __builtin_amdgcn_s_barrier();
    cur^=1;
  }
}

// ---------------- fused QKV projection ----------------
// Q stored PRE-SCALED by 0.125*log2(e) so attn uses bare v_exp_f32 (2^x).
// V stored PERMUTED within each 32-key chunk so attn's PV A-fragment needs no shuffles.
__global__ __launch_bounds__(256) void qkv_gemm(const short* __restrict__ xb,
    const short* __restrict__ wqb, const short* __restrict__ wkb, const short* __restrict__ wvb,
    const float* __restrict__ bq, const float* __restrict__ bk, const float* __restrict__ bv,
    short* __restrict__ qo, short* __restrict__ ko, short* __restrict__ vfo)
{
  __shared__ short As[8192], Bs[8192];
  const int tid=threadIdx.x, l=tid&63, w=tid>>6;
  const int bcol0=blockIdx.x*128, brow0=blockIdx.y*128;
  const int mat=bcol0>>10, n0=bcol0&1023;
  const short* Wm   = mat==0?wqb:(mat==1?wkb:wvb);
  const float* bias = mat==0?bq:(mat==1?bk:bv);
  v4f acc[4][4];
  v4f vz={0.f,0.f,0.f,0.f};
  #pragma unroll
  for(int m=0;m<4;++m)
    #pragma unroll
    for(int n=0;n<4;++n) acc[m][n]=vz;
  gemm_core16(xb, Wm, brow0, n0, tid, As, Bs, acc);
  const int wr=(w>>1)*64, wc=(w&1)*64;
  const float qscale = 0.18033688011112042f;   // 0.125 * log2(e)
  #pragma unroll
  for(int m=0;m<4;++m)
  #pragma unroll
  for(int n=0;n<4;++n)
  #pragma unroll
  for(int r=0;r<4;++r){
    int row=brow0+wr+m*16+(l>>4)*4+r;       // 0..4095  (b*2048+s)
    int col=n0+wc+n*16+(l&15);              // 0..1023 within mat
    float v=acc[m][n][r]+bias[col];
    int b=row>>11, s=row&2047, h=col>>6, dk=col&63;
    int bh=b*16+h;
    if(mat==0)      qo[((size_t)bh*2048+s)*64+dk]=f2bf(v*qscale);
    else if(mat==1) ko[((size_t)bh*2048+s)*64+dk]=f2bf(v);
    else{
      int kb=s>>9, c=(s>>5)&15, ki=s&31;
      int g2=(ki>>2)&3, j=(ki>>4)*4+(ki&3);
      int lane2=g2*16+(dk&15);
      vfo[((((size_t)bh*4+kb)*16+c)*4+(size_t)(dk>>4))*512 + lane2*8 + j]=f2bf(v);
    }
  }
}

// ---------------- per-(bh,kb) V column sums, 4-wave parallel ----------------
__global__ __launch_bounds__(256) void vbsum_kernel(const short* __restrict__ vf, float* __restrict__ vbp)
{
  __shared__ float red[4][4][16];     // [wave][dt][d16]
  const int bh=blockIdx.x, kb=blockIdx.y, tid=threadIdx.x, wv=tid>>6, l=tid&63;
  const short* base = vf + ((size_t)(bh*4+kb))*16*4*512;
  float acc[4]={0.f,0.f,0.f,0.f};
  #pragma unroll
  for(int cc=0;cc<4;++cc){
    int c=wv*4+cc;
    #pragma unroll
    for(int dt=0;dt<4;++dt){
      v8s vv=*(const v8s*)(base + ((size_t)(c*4+dt))*512 + l*8);
      float s=0.f;
      #pragma unroll
      for(int j=0;j<8;++j) s+=bf2f((unsigned short)vv[j]);
      acc[dt]+=s;
    }
  }
  #pragma unroll
  for(int dt=0;dt<4;++dt){
    acc[dt]+=__shfl_xor(acc[dt],16);
    acc[dt]+=__shfl_xor(acc[dt],32);
  }
  if(l<16){
    #pragma unroll
    for(int dt=0;dt<4;++dt) red[wv][dt][l]=acc[dt];
  }
  __syncthreads();
  if(tid<64){
    int dt=tid>>4, d=tid&15;
    float s=(red[0][dt][d]+red[1][dt][d])+(red[2][dt][d]+red[3][dt][d]);
    vbp[(size_t)(bh*4+kb)*64 + dt*16 + d]=s;
  }
}

// ---------------- fused double-softmax attention: SINGLE-PASS, bf16 score cache ----------
// LOAD-BALANCED: each block does TWO q-tiles sequentially, qt=31-y (heavy) then qt=y
// (light) -> exactly 5 windows per block for every y (dispatch-order independent, G16).
// Grid (32 bh, 16 y) = 512 blocks = 2/CU, all co-resident, uniform finish.
// NO launch-bounds cap (caps spill/squeeze: R9/R21/R26); no setprio (R18); bh fast (R22);
// 32KB kbuf (64KB pipelining regressed: R28).
__global__ __launch_bounds__(256) void attn_kernel(
  const short* __restrict__ q, const short* __restrict__ k, const short* __restrict__ vf,
  const float* __restrict__ vbp, short* __restrict__ attn)
{
  __shared__ short kbuf[16384];       // 32KB: 256 keys x 64d, XOR-swizzled 16B slots
  const int tid=threadIdx.x, l=tid&63, wv=tid>>6;
  const int bh=blockIdx.x;
  const int g=l>>4, q16=l&15;
  const int b=bh>>4, h=bh&15;

  const short* qbase = q + (size_t)bh*2048*64;
  const short* kbase = k + (size_t)bh*2048*64;
  v4f vz={0.f,0.f,0.f,0.f};

  auto stage=[&](int kb2,int hb2){
    #pragma unroll
    for (int i=0;i<8;++i){
      int idx=i*256+tid, key=idx>>3, p=idx&7, pp=p^(key&7);
      const short* gp = kbase + (size_t)(kb2*512+hb2*256+key)*64 + pp*8;
      __builtin_amdgcn_global_load_lds((const AS1 void*)gp,
          (AS3 void*)((char*)kbuf + idx*16), 16, 0, 0);
    }
  };

// QK^T tile CT -> exp2'd scores packed into sc16, d1acc accumulated
#define QKE(CT)                                                         \
  { int krow=((CT)&15)*16+q16;                                          \
    int s0=g^(krow&7), s1=(g+4)^(krow&7);                               \
    v8s k0=*(const v8s*)&kbuf[(krow*8+s0)*8];                           \
    v8s k1=*(const v8s*)&kbuf[(krow*8+s1)*8];                           \
    v4f t=mfma16(k0,qa0,vz);                                            \
    v4f e4=mfma16(k1,qa1,t);                                            \
    v4f ev;                                                             \
    _Pragma("unroll")                                                   \
    for (int r=0;r<4;++r){                                              \
      float s=e4[r];                                                    \
      if (diag && kb*512+(CT)*16+g*4+r > qglob) s=-1e38f;               \
      ev[r]=fexp2(s);                                                   \
      d1acc+=ev[r];                                                     \
    }                                                                   \
    sc16[(CT)*2]=pk2(ev[0],ev[1]); sc16[(CT)*2+1]=pk2(ev[2],ev[3]);     \
  }

// PV chunk C from cached scores: w = 2^(e*d1i) - 1
#define PVC(C)                                                          \
  { unsigned a0=sc16[4*(C)], a1=sc16[4*(C)+1];                          \
    unsigned b0=sc16[4*(C)+2], b1=sc16[4*(C)+3];                        \
    float w0=fexp2(bf2f((unsigned short)(a0&0xffffu))*d1i)-1.0f;        \
    float w1=fexp2(bf2fhi(a0)*d1i)-1.0f;                                \
    float w2=fexp2(bf2f((unsigned short)(a1&0xffffu))*d1i)-1.0f;        \
    float w3=fexp2(bf2fhi(a1)*d1i)-1.0f;                                \
    float w4=fexp2(bf2f((unsigned short)(b0&0xffffu))*d1i)-1.0f;        \
    float w5=fexp2(bf2fhi(b0)*d1i)-1.0f;                                \
    float w6=fexp2(bf2f((unsigned short)(b1&0xffffu))*d1i)-1.0f;        \
    float w7=fexp2(bf2fhi(b1)*d1i)-1.0f;                                \
    zacc+=((w0+w1)+(w2+w3))+((w4+w5)+(w6+w7));                          \
    union { v4u u; v8s s; } pa;                                         \
    pa.u[0]=pk2(w0,w1); pa.u[1]=pk2(w2,w3);                             \
    pa.u[2]=pk2(w4,w5); pa.u[3]=pk2(w6,w7);                             \
    const short* vfp = vf + ((((size_t)bh*4+kb)*16+(C))*4)*512 + l*8;   \
    _Pragma("unroll")                                                   \
    for (int dt=0;dt<4;++dt){                                           \
      v8s vfr=*(const v8s*)(vfp + (size_t)dt*512);                      \
      o[dt]=mfma16(pa.s,vfr,o[dt]);                                     \
    }                                                                   \
  }

  #pragma unroll 1
  for (int half=0; half<2; ++half){
    const int qt = half ? (int)blockIdx.y : 31-(int)blockIdx.y;  // heavy then light: 5 windows total
    const int qb = qt>>3;
    const int qrow0 = qt*64+wv*16;
    const int qglob = qrow0+q16;
    const short* qp = qbase + (size_t)(qrow0+q16)*64 + g*8;
    v8s qa0=*(const v8s*)qp, qa1=*(const v8s*)(qp+32);

    v4f o[4];
    #pragma unroll
    for(int dt=0;dt<4;++dt) o[dt]=vz;
    float zacc=0.f;
    unsigned sc16[64];                // 32 tiles x 4 scores, 2^x applied, packed bf16 pairs

    for (int kb=0; kb<=qb; ++kb){
      const bool diag=(kb==qb);
      // pair-rounded last live tile (odd): extra tile fully masked -> stores exact 0s
      const int tmax2 = diag ? (((qt&7)*4+wv)|1) : 31;
      const int blkhi = diag ? ((qt&7)*4+3) : 31;  // block-uniform
      float d1acc=0.f;
      stage(kb,0); __syncthreads();
      #pragma unroll
      for (int ct=0;ct<16;++ct) if (ct<=tmax2) QKE(ct)
      __syncthreads();
      if (blkhi>=16){
        stage(kb,1); __syncthreads();
        #pragma unroll
        for (int ct=16;ct<32;++ct) if (ct<=tmax2) QKE(ct)
        __syncthreads();
      }
      float d1=d1acc;
      d1+=__shfl_xor(d1,16); d1+=__shfl_xor(d1,32);
      const float d1i=1.44269504f/d1;
      #pragma unroll
      for (int c=0;c<16;++c) if (2*c<=tmax2) PVC(c)
    }

    // ---- epilogue: Z per q-row, baseline = total V sum (weight 1), Z base 2048 ----
    float z=zacc;
    z+=__shfl_xor(z,16); z+=__shfl_xor(z,32);
    float base[4];
    #pragma unroll
    for (int dt=0;dt<4;++dt){
      float s=0.f;
      #pragma unroll
      for (int kk=0;kk<4;++kk) s+=vbp[(size_t)(bh*4+kk)*64 + dt*16 + q16];
      base[dt]=s;
    }
    #pragma unroll
    for (int r=0;r<4;++r){
      float zr=__shfl(z, g*4+r);
      float inv=1.0f/(2048.0f+zr);
      int rowi=qrow0+g*4+r;
      size_t obase=((size_t)b*2048+rowi)*1024 + h*64;
      #pragma unroll
      for (int dt=0;dt<4;++dt)
        attn[obase + dt*16 + q16] = f2bf((o[dt][r]+base[dt])*inv);
    }
  }
#undef QKE
#undef PVC
}

// ---------------- output projection (A bf16, B bf16 pre-converted, out fp32) -------------
__global__ __launch_bounds__(256) void oproj_gemm(const short* __restrict__ at,
    const short* __restrict__ wob, const float* __restrict__ bo, float* __restrict__ out)
{
  __shared__ short As[8192], Bs[8192];
  const int tid=threadIdx.x, l=tid&63, w=tid>>6;
  const int bcol0=blockIdx.x*128, brow0=blockIdx.y*128;
  v4f acc[4][4];
  v4f vz={0.f,0.f,0.f,0.f};
  #pragma unroll
  for(int m=0;m<4;++m)
    #pragma unroll
    for(int n=0;n<4;++n) acc[m][n]=vz;
  gemm_core16(at, wob, brow0, bcol0, tid, As, Bs, acc);
  const int wr=(w>>1)*64, wc=(w&1)*64;
  #pragma unroll
  for(int m=0;m<4;++m)
  #pragma unroll
  for(int n=0;n<4;++n)
  #pragma unroll
  for(int r=0;r<4;++r){
    int row=brow0+wr+m*16+(l>>4)*4+r;
    int col=bcol0+wc+n*16+(l&15);
    out[(size_t)row*1024+col]=acc[m][n][r]+bo[col];
  }
}

extern "C" void kernel_launch(void* const* d_in, const int* in_sizes, int n_in,
                              void* d_out, int out_size, void* d_ws, size_t ws_size,
                              hipStream_t stream)
{
  const float* x  =(const float*)d_in[0];
  const float* Wq =(const float*)d_in[1];
  const float* bq =(const float*)d_in[2];
  const float* Wk =(const float*)d_in[3];
  const float* bk =(const float*)d_in[4];
  const float* Wv =(const float*)d_in[5];
  const float* bv =(const float*)d_in[6];
  const float* Wo =(const float*)d_in[7];
  const float* bo =(const float*)d_in[8];
  float* out=(float*)d_out;
  char* ws=(char*)d_ws;
  // ws (32 MiB): [0,8M)=xb then at_ws; [8M)=q then wob (q dead after attn); [16M)=k; [24M)=vf.
  // d_out doubles as scratch until oproj overwrites it:
  //   [0,2M)=wqb, [2M,4M)=wkb, [4M,6M)=wvb (bf16), [7M)=vbp (fp32, 32KB).
  short* xb_ws =(short*)(ws);
  short* at_ws =(short*)(ws);
  short* q_ws  =(short*)(ws + ((size_t)8<<20));
  short* wob_ws=(short*)(ws + ((size_t)8<<20));
  short* k_ws  =(short*)(ws + ((size_t)16<<20));
  short* vf_ws =(short*)(ws + ((size_t)24<<20));
  char*  outb  =(char*)d_out;
  short* wqb   =(short*)(outb);
  short* wkb   =(short*)(outb + ((size_t)2<<20));
  short* wvb   =(short*)(outb + ((size_t)4<<20));
  float* vbp_ws=(float*)(outb + ((size_t)7<<20));

  convert_kernel<<<dim3(7168),256,0,stream>>>(x,Wq,Wk,Wv,xb_ws,wqb,wkb,wvb);
  qkv_gemm<<<dim3(24,32),256,0,stream>>>(xb_ws,wqb,wkb,wvb,bq,bk,bv,q_ws,k_ws,vf_ws);
  vbsum_kernel<<<dim3(32,4),256,0,stream>>>(vf_ws,vbp_ws);
  attn_kernel<<<dim3(32,16),256,0,stream>>>(q_ws,k_ws,vf_ws,vbp_ws,at_ws);
  convertW_kernel<<<dim3(1024),256,0,stream>>>(Wo,wob_ws);
  oproj_gemm<<<dim3(8,32),256,0,stream>>>(at_ws,wob_ws,bo,out);
}